// Round 2
// baseline (6182.899 us; speedup 1.0000x reference)
//
#include <hip/hip_runtime.h>
#include <hip/hip_bf16.h>

#define N_    20000
#define S_    20
#define NC_   400000
#define EC_   2000000
#define EB_   200000
#define NIN_  64
#define HOP_  16
#define D_    80
#define NOUT_ 64
#define NB_   1563   // ceil(NC/256)

// ---------------- scan utility (block of 256 = 4 waves) ----------------
__device__ __forceinline__ int blockExclScan(int v, int tid, int* lds, int* total) {
    int lane = tid & 63;
    int w = tid >> 6;
    int x = v;
    #pragma unroll
    for (int off = 1; off < 64; off <<= 1) {
        int y = __shfl_up(x, off, 64);
        if (lane >= off) x += y;
    }
    if (lane == 63) lds[w] = x;
    __syncthreads();
    if (tid == 0) {
        int acc = 0;
        #pragma unroll
        for (int i = 0; i < 4; i++) { int t = lds[i]; lds[4 + i] = acc; acc += t; }
        lds[8] = acc;
    }
    __syncthreads();
    int res = x - v + lds[4 + w];
    *total = lds[8];
    return res;
}

// ---------------- CSR build ----------------
__global__ __launch_bounds__(256) void k_degree(const int* __restrict__ eidx, int* __restrict__ deg) {
    int e = blockIdx.x * 256 + threadIdx.x;
    if (e >= EC_) return;
    atomicAdd(&deg[eidx[EC_ + e]], 1);
}

__global__ __launch_bounds__(256) void k_bsum(const int* __restrict__ deg, int* __restrict__ bsums) {
    __shared__ int lds[9];
    int i = blockIdx.x * 256 + threadIdx.x;
    int v = (i < NC_) ? deg[i] : 0;
    int tot;
    blockExclScan(v, threadIdx.x, lds, &tot);
    if (threadIdx.x == 0) bsums[blockIdx.x] = tot;
}

__global__ __launch_bounds__(256) void k_scan_bsums(int* __restrict__ bsums) {
    __shared__ int lds[9];
    int carry = 0;
    for (int base = 0; base < NB_; base += 256) {
        int i = base + threadIdx.x;
        int v = (i < NB_) ? bsums[i] : 0;
        int tot;
        int ex = blockExclScan(v, threadIdx.x, lds, &tot);
        if (i < NB_) bsums[i] = ex + carry;
        carry += tot;
        __syncthreads();
    }
}

__global__ __launch_bounds__(256) void k_scan_apply(
    int* __restrict__ cursor /* deg in, cursor out */, int* __restrict__ start,
    const int* __restrict__ bsums)
{
    __shared__ int lds[9];
    int i = blockIdx.x * 256 + threadIdx.x;
    int v = (i < NC_) ? cursor[i] : 0;
    int tot;
    int ex = blockExclScan(v, threadIdx.x, lds, &tot);
    if (i < NC_) {
        int s = ex + bsums[blockIdx.x];
        start[i] = s;
        cursor[i] = s;
    }
    if (blockIdx.x == 0 && threadIdx.x == 0) start[NC_] = EC_;
}

// e2[pos] = {src, emap}; e1x[pos] = {mapper[src], hop[src]+1}
__global__ __launch_bounds__(256) void k_fill(
    const int* __restrict__ eidx, const int* __restrict__ emap,
    const int* __restrict__ mapper, const int* __restrict__ hop,
    int* __restrict__ cursor, int2* __restrict__ e2, int2* __restrict__ e1x)
{
    int e = blockIdx.x * 256 + threadIdx.x;
    if (e >= EC_) return;
    int src = eidx[e];
    int dst = eidx[EC_ + e];
    int pos = atomicAdd(&cursor[dst], 1);
    e2[pos] = make_int2(src, emap[e]);
    e1x[pos] = make_int2(mapper[src], hop[src] + 1);
}

// ---------------- GINE layer 1 (h0 computed on the fly) ----------------
__global__ __launch_bounds__(320) void k_layer1(
    float* __restrict__ hout,
    const float* __restrict__ x, const float* __restrict__ ht,
    const int* __restrict__ mapper, const int* __restrict__ hop,
    const float* __restrict__ ea, const int* __restrict__ start,
    const int2* __restrict__ e2, const int2* __restrict__ e1x,
    const float* __restrict__ W, const float* __restrict__ g, const float* __restrict__ b)
{
    __shared__ float sW[D_ * D_];      // 25.6 KB
    __shared__ float sV[4][D_];
    int tid = threadIdx.x;
    for (int t = tid; t < D_ * D_; t += 320) sW[t] = W[t];
    int grp = tid / D_;
    int d = tid - grp * D_;
    float gd = g[d], bd = b[d];
    bool lo = d < 64;
    __syncthreads();
    for (int chunk = blockIdx.x; chunk < NC_ / 4; chunk += gridDim.x) {
        int node = chunk * 4 + grp;
        int mn = mapper[node], hn = hop[node] + 1;
        float hd = lo ? x[(size_t)mn * 64 + d] : ht[hn * 16 + (d - 64)];
        float acc = 0.f;
        int s0 = start[node], s1 = start[node + 1];
        for (int e = s0; e < s1; e++) {
            int2 em = e2[e];
            int2 ex = e1x[e];
            float hs = lo ? x[(size_t)ex.x * 64 + d] : ht[ex.y * 16 + (d - 64)];
            float m = hs + ea[(size_t)em.y * D_ + d];
            acc += fmaxf(m, 0.f);
        }
        sV[grp][d] = hd + acc;
        __syncthreads();
        float dot = 0.f;
        #pragma unroll
        for (int k = 0; k < D_; k++) dot += sV[grp][k] * sW[k * D_ + d];
        hout[(size_t)node * D_ + d] = fmaxf(gd * dot + bd, 0.f) + hd;
        __syncthreads();
    }
}

// ---------------- fused layer2 + output encoder + pooling (two passes) ----------------
// PASS1: centroid (gc) + sub-pool (gs) + counts. PASS2: ctx-pool (gx).
template<bool PASS1>
__global__ __launch_bounds__(320) void k_l2pool(
    const float* __restrict__ h1, const float* __restrict__ ea,
    const int* __restrict__ start, const int2* __restrict__ e2,
    const float* __restrict__ W2, const float* __restrict__ g2, const float* __restrict__ b2,
    const float* __restrict__ oe_w, const float* __restrict__ oe_b,
    const float* __restrict__ mw, const float* __restrict__ mb,
    const float* __restrict__ mg, const float* __restrict__ mbt,
    const float* __restrict__ gate_w, const float* __restrict__ gate_b,
    const float* __restrict__ gc_w, const float* __restrict__ gc_b,
    const float* __restrict__ ht, const int* __restrict__ hop,
    const int* __restrict__ mapper, const int* __restrict__ batchv,
    float* __restrict__ cent, float* __restrict__ poolbuf,
    int* __restrict__ cntb, int* __restrict__ cntm)
{
    __shared__ float sW[D_ * D_];     // 25.6 KB
    __shared__ float sOE[D_ * 64];    // 20 KB
    __shared__ float sM[64 * 64];     // 16 KB
    __shared__ float sV[4][D_];       // 1.25 KB
    __shared__ float sC[4][64];       // 1 KB   -> total 64.8 KB? no: 63.9 KB
    int tid = threadIdx.x;
    for (int t = tid; t < D_ * D_; t += 320) sW[t] = W2[t];
    for (int t = tid; t < D_ * 64; t += 320) sOE[t] = oe_w[t];
    for (int t = tid; t < 64 * 64; t += 320) sM[t] = mw[t];
    int grp = tid / D_;
    int d = tid - grp * D_;
    bool lo = d < 64;
    int dl = lo ? d : 0;
    float gd = g2[d], bd = b2[d];
    float r_oeb = oe_b[dl];
    float r_mb = mb[dl], r_mg = mg[dl], r_mbt = mbt[dl];
    float r_gb = gate_b[dl];
    float r_gcb = PASS1 ? gc_b[dl] : 0.f;
    __syncthreads();
    for (int chunk = blockIdx.x; chunk < NC_ / 4; chunk += gridDim.x) {
        int node = chunk * 4 + grp;
        float hd = h1[(size_t)node * D_ + d];
        float acc = 0.f;
        int s0 = start[node], s1 = start[node + 1];
        for (int e = s0; e < s1; e++) {
            int2 em = e2[e];
            float m = h1[(size_t)em.x * D_ + d] + ea[(size_t)em.y * D_ + d];
            acc += fmaxf(m, 0.f);
        }
        sV[grp][d] = hd + acc;
        __syncthreads();
        float dot = 0.f;
        #pragma unroll
        for (int k = 0; k < D_; k++) dot += sV[grp][k] * sW[k * D_ + d];
        float h2v = fmaxf(gd * dot + bd, 0.f) + hd;
        __syncthreads();
        sV[grp][d] = h2v;
        __syncthreads();
        float cb = 0.f, gate = 0.f, gc = 0.f;
        if (lo) {
            cb = r_oeb;
            #pragma unroll
            for (int k = 0; k < D_; k++) cb += sV[grp][k] * sOE[k * 64 + d];
            int hn = hop[node] + 1;
            float gv = r_gb;
            #pragma unroll
            for (int k = 0; k < 16; k++) gv += ht[hn * 16 + k] * gate_w[k * 64 + d];
            gate = 1.f / (1.f + __expf(-gv));
            if (PASS1) {
                float gcv = r_gcb;
                #pragma unroll
                for (int k = 0; k < 16; k++) gcv += ht[hn * 16 + k] * gc_w[k * 64 + d];
                gc = 1.f / (1.f + __expf(-gcv));
            }
            sC[grp][d] = cb;
        }
        __syncthreads();
        if (lo) {
            float mv = r_mb;
            #pragma unroll
            for (int k = 0; k < 64; k++) mv += sC[grp][k] * sM[k * 64 + d];
            mv = fmaxf(r_mg * mv + r_mbt, 0.f) * gate;
            if (PASS1) {
                int bb = batchv[node];
                int mm = mapper[node];
                if (mm == bb) atomicAdd(&cent[(size_t)bb * 64 + d], cb * gc);
                atomicAdd(&poolbuf[(size_t)bb * 64 + d], mv);
                if (d == 0) { atomicAdd(&cntb[bb], 1); atomicAdd(&cntm[mm], 1); }
            } else {
                int mm = mapper[node];
                atomicAdd(&poolbuf[(size_t)mm * 64 + d], mv);
            }
        }
        __syncthreads();
    }
}

// ---------------- final: combine pools + out_encoder ----------------
__global__ __launch_bounds__(256) void k_final(
    const float* __restrict__ cent, const float* __restrict__ subp, const float* __restrict__ ctxp,
    const int* __restrict__ cntb, const int* __restrict__ cntm,
    const float* __restrict__ fo_w, const float* __restrict__ fo_b,
    const float* __restrict__ fo_g, const float* __restrict__ fo_bt,
    float* __restrict__ out)
{
    __shared__ float sW[64 * 64];
    int tid = threadIdx.x;
    for (int t = tid; t < 4096; t += 256) sW[t] = fo_w[t];
    int d = tid & 63, grp = tid >> 6;
    float rb = fo_b[d], rg = fo_g[d], rbt = fo_bt[d];
    __syncthreads();
    for (int n = blockIdx.x * 4 + grp; n < N_; n += gridDim.x * 4) {
        float cb = (float)max(cntb[n], 1);
        float cm = (float)max(cntm[n], 1);
        size_t o = (size_t)n * 64 + d;
        float r = cent[o] + subp[o] / cb + ctxp[o] / cm;
        float dot = rb;
        #pragma unroll
        for (int k = 0; k < 64; k++) dot += __shfl(r, k) * sW[k * 64 + d];
        out[o] = rg * dot + rbt;
    }
}

// ---------------- launch ----------------
extern "C" void kernel_launch(void* const* d_in, const int* in_sizes, int n_in,
                              void* d_out, int out_size, void* d_ws, size_t ws_size,
                              hipStream_t stream) {
    const float* x         = (const float*)d_in[0];
    const float* edge_attr = (const float*)d_in[1];
    const float* hop_table = (const float*)d_in[2];
    const float* conv_w1   = (const float*)d_in[3];
    const float* bn1_g     = (const float*)d_in[4];
    const float* bn1_b     = (const float*)d_in[5];
    const float* conv_w2   = (const float*)d_in[6];
    const float* bn2_g     = (const float*)d_in[7];
    const float* bn2_b     = (const float*)d_in[8];
    const float* oe_w      = (const float*)d_in[9];
    const float* oe_b      = (const float*)d_in[10];
    const float* sub_w     = (const float*)d_in[11];
    const float* sub_b     = (const float*)d_in[12];
    const float* sub_g     = (const float*)d_in[13];
    const float* sub_bt    = (const float*)d_in[14];
    const float* ctx_w     = (const float*)d_in[15];
    const float* ctx_b     = (const float*)d_in[16];
    const float* ctx_g     = (const float*)d_in[17];
    const float* ctx_bt    = (const float*)d_in[18];
    const float* gc_w      = (const float*)d_in[19];
    const float* gc_b      = (const float*)d_in[20];
    const float* gs_w      = (const float*)d_in[21];
    const float* gs_b      = (const float*)d_in[22];
    const float* gx_w      = (const float*)d_in[23];
    const float* gx_b      = (const float*)d_in[24];
    const float* fo_w      = (const float*)d_in[25];
    const float* fo_b      = (const float*)d_in[26];
    const float* fo_g      = (const float*)d_in[27];
    const float* fo_bt     = (const float*)d_in[28];
    const int* nodes_mapper  = (const int*)d_in[29];
    const int* edges_mapper  = (const int*)d_in[30];
    const int* edge_index    = (const int*)d_in[31];
    const int* batch         = (const int*)d_in[32];
    const int* hop_indicator = (const int*)d_in[33];
    float* out = (float*)d_out;

    // workspace bump allocator (256B aligned) — total ~179 MB
    size_t off = 0;
    auto alloc = [&](size_t bytes) -> char* {
        char* p = (char*)d_ws + off;
        off = (off + bytes + 255) & ~(size_t)255;
        return p;
    };
    float* h1    = (float*)alloc((size_t)NC_ * D_ * 4);   // 128 MB
    int*   start = (int*)alloc((size_t)(NC_ + 1) * 4);    // 1.6 MB
    int*   cursor= (int*)alloc((size_t)NC_ * 4);          // 1.6 MB
    int*   bsums = (int*)alloc(2048 * 4);
    int2*  e2    = (int2*)alloc((size_t)EC_ * 8);         // 16 MB
    int2*  e1x   = (int2*)alloc((size_t)EC_ * 8);         // 16 MB
    float* cent  = (float*)alloc((size_t)N_ * 64 * 4);    // 5.12 MB
    float* subp  = (float*)alloc((size_t)N_ * 64 * 4);    // 5.12 MB
    float* ctxp  = (float*)alloc((size_t)N_ * 64 * 4);    // 5.12 MB
    int*   cntb  = (int*)alloc((size_t)N_ * 4);
    int*   cntm  = (int*)alloc((size_t)N_ * 4);
    (void)ws_size; (void)in_sizes; (void)n_in; (void)out_size;

    // zero accumulators (every call — harness does not re-poison between replays)
    hipMemsetAsync(cursor, 0, (size_t)NC_ * 4, stream);
    hipMemsetAsync(cent, 0, (size_t)N_ * 64 * 4, stream);
    hipMemsetAsync(subp, 0, (size_t)N_ * 64 * 4, stream);
    hipMemsetAsync(ctxp, 0, (size_t)N_ * 64 * 4, stream);
    hipMemsetAsync(cntb, 0, (size_t)N_ * 4, stream);
    hipMemsetAsync(cntm, 0, (size_t)N_ * 4, stream);

    // CSR build (reused by layer1 and both fused passes)
    k_degree<<<(EC_ + 255) / 256, 256, 0, stream>>>(edge_index, cursor);
    k_bsum<<<NB_, 256, 0, stream>>>(cursor, bsums);
    k_scan_bsums<<<1, 256, 0, stream>>>(bsums);
    k_scan_apply<<<NB_, 256, 0, stream>>>(cursor, start, bsums);
    k_fill<<<(EC_ + 255) / 256, 256, 0, stream>>>(edge_index, edges_mapper,
                                                  nodes_mapper, hop_indicator,
                                                  cursor, e2, e1x);

    // layer 1 (h0 on the fly) -> h1
    k_layer1<<<2560, 320, 0, stream>>>(h1, x, hop_table, nodes_mapper, hop_indicator,
                                       edge_attr, start, e2, e1x, conv_w1, bn1_g, bn1_b);

    // fused layer2 + head, two passes
    k_l2pool<true><<<2560, 320, 0, stream>>>(h1, edge_attr, start, e2,
                                             conv_w2, bn2_g, bn2_b, oe_w, oe_b,
                                             sub_w, sub_b, sub_g, sub_bt,
                                             gs_w, gs_b, gc_w, gc_b,
                                             hop_table, hop_indicator, nodes_mapper, batch,
                                             cent, subp, cntb, cntm);
    k_l2pool<false><<<2560, 320, 0, stream>>>(h1, edge_attr, start, e2,
                                              conv_w2, bn2_g, bn2_b, oe_w, oe_b,
                                              ctx_w, ctx_b, ctx_g, ctx_bt,
                                              gx_w, gx_b, gc_w, gc_b,
                                              hop_table, hop_indicator, nodes_mapper, batch,
                                              cent, ctxp, cntb, cntm);

    // final combine + out encoder
    k_final<<<1280, 256, 0, stream>>>(cent, subp, ctxp, cntb, cntm,
                                      fo_w, fo_b, fo_g, fo_bt, out);
}